// Round 10
// baseline (26.075 us; speedup 1.0000x reference)
//
#include <hip/hip_runtime.h>
#include <math.h>
#include <stdint.h>

// ---------------------------------------------------------------------------
// VNFrameEstimator R10: R4's coalesced global_load_lds staging skeleton
// (1KB contiguous per wave-instruction) combined with R9's all-f32 math.
//  - per block: NT=4 tiles x 16 batches, double-buffered 2x24KB LDS staging,
//    source-swizzled (q ^= (q>>3)&7) so per-lane 96B ds_read chunks are
//    bank-conflict-free while global reads stay perfectly coalesced.
//  - f32 normalize (raw v_rsq on fmaxf-guarded n2), 8 moments (zz via trace
//    identity), 16-lane DPP row_ror rotate-reduce.
//  - tail: full wave, 1 thread/batch f32 3x3 Jacobi (4 sweeps), sort,
//    sign-fix, cross; frames staged in LDS; coalesced dwordx4 epilogue.
// ---------------------------------------------------------------------------

#define BLOCK      256
#define TILE_B     16                    // batches per tile
#define TILE_QUADS (TILE_B * 96)         // 1536 quads = 24 KB
#define NT         4                     // tiles per block
#define BPB        (TILE_B * NT)         // 64 batches per block
#define NSTAGE     6                     // 6 x (4 waves x 1 KB) = 24 KB

// quad-index involution within each 64-quad row: XOR bits[2:0] with bits[5:3]
__device__ __forceinline__ uint32_t swz(uint32_t q) { return q ^ ((q >> 3) & 7u); }

// f32 rotate within the 16-lane DPP row (pure VALU). CTRL: ROW_ROR:N = 0x120|N.
template <int CTRL>
__device__ __forceinline__ float ror16_f32(float v) {
    union { float f; int i; } u, r;
    u.f = v;
    r.i = __builtin_amdgcn_mov_dpp(u.i, CTRL, 0xF, 0xF, true);
    return r.f;
}

// f32 1/sqrt, ~1 ulp (HW seed + 1 NR)
__device__ __forceinline__ float frsqrt(float x) {
    float r = __builtin_amdgcn_rsqf(x);
    return r * fmaf(-0.5f * x, r * r, 1.5f);
}
// f32 1/x, ~1 ulp (HW seed + 1 NR)
__device__ __forceinline__ float frcp(float x) {
    float r = __builtin_amdgcn_rcpf(x);
    return r * fmaf(-x, r, 2.0f);
}

// One f32 Jacobi rotation zeroing A[P][Q]; R is the remaining index.
template <int P, int Q, int R>
__device__ __forceinline__ void jrot(float (&A)[3][3], float (&V)[3][3]) {
    float apq = A[P][Q];
    if (fabsf(apq) > 1e-12f) {
        float theta = (A[Q][Q] - A[P][P]) * 0.5f * frcp(apq);
        float q = fmaf(theta, theta, 1.0f);
        float sq = q * frsqrt(q);                  // sqrt(theta^2+1)
        float t = frcp(fabsf(theta) + sq);
        if (theta < 0.0f) t = -t;
        float c = frsqrt(fmaf(t, t, 1.0f));
        float s = t * c;
        float apq_t = t * apq;
        A[P][P] = A[P][P] - apq_t;
        A[Q][Q] = A[Q][Q] + apq_t;
        A[P][Q] = 0.0f;
        A[Q][P] = 0.0f;
        float apr = A[P][R], aqr = A[Q][R];
        A[P][R] = fmaf(c, apr, -s * aqr); A[R][P] = A[P][R];
        A[Q][R] = fmaf(s, apr,  c * aqr); A[R][Q] = A[Q][R];
#pragma unroll
        for (int i = 0; i < 3; ++i) {
            float vip = V[i][P], viq = V[i][Q];
            V[i][P] = fmaf(c, vip, -s * viq);
            V[i][Q] = fmaf(s, vip,  c * viq);
        }
    }
}

// accumulate 8 vectors (24 floats) into 8 f32 moments
// m: [0]=xx [1]=xy [2]=xz [3]=yy [4]=yz [5]=sx [6]=sy [7]=sz   (zz via trace)
__device__ __forceinline__ void accum8(const float (&f)[24], float (&m)[8]) {
#pragma unroll
    for (int k = 0; k < 8; ++k) {
        float fx = f[3 * k + 0];
        float fy = f[3 * k + 1];
        float fz = f[3 * k + 2];
        float n2 = fmaf(fx, fx, fmaf(fy, fy, fz * fz));
        // rsq(max(n2,1e-24)) == reference 1e-12 norm clamp exactly
        float inv = __builtin_amdgcn_rsqf(fmaxf(n2, 1e-24f));
        float x = fx * inv;
        float y = fy * inv;
        float z = fz * inv;
        m[0] = fmaf(x, x, m[0]);
        m[1] = fmaf(x, y, m[1]);
        m[2] = fmaf(x, z, m[2]);
        m[3] = fmaf(y, y, m[3]);
        m[4] = fmaf(y, z, m[4]);
        m[5] += x; m[6] += y; m[7] += z;
    }
}

__device__ __forceinline__ void reduce16(float (&m)[8]) {
#pragma unroll
    for (int k = 0; k < 8; ++k) m[k] += ror16_f32<0x121>(m[k]);
#pragma unroll
    for (int k = 0; k < 8; ++k) m[k] += ror16_f32<0x122>(m[k]);
#pragma unroll
    for (int k = 0; k < 8; ++k) m[k] += ror16_f32<0x124>(m[k]);
#pragma unroll
    for (int k = 0; k < 8; ++k) m[k] += ror16_f32<0x128>(m[k]);
}

__global__ __launch_bounds__(BLOCK) void vn_fused(
    const float* __restrict__ vf, float* __restrict__ out, int B) {
    __shared__ __align__(16) float sbuf[2][TILE_QUADS * 4];   // 2 x 24 KB
    __shared__ __align__(16) float sA[BPB][9];                // 2.3 KB

    const int tid  = threadIdx.x;
    const int wave = tid >> 6;
    const int lane = tid & 63;
    const uint32_t lswz = (uint32_t)lane ^ ((uint32_t)lane >> 3);

    const size_t maxQuad = (size_t)B * 96;
    const size_t tile0   = (size_t)blockIdx.x * NT;

    // stage one 24KB tile: linear LDS writes, source-swizzled global reads.
    // each global_load_lds covers a contiguous 1KB row per wave-instruction.
    auto stage = [&](int bufi, int t) {
#pragma unroll
        for (int i = 0; i < NSTAGE; ++i) {
            const uint32_t rowQuad = (uint32_t)(i * 4 + wave) * 64;
            size_t gq = (tile0 + (size_t)t) * TILE_QUADS + rowQuad + lswz;
            if (gq >= maxQuad) gq = maxQuad - 1;    // clamp (pad batches)
            const float* gsrc = vf + gq * 4;
            float* ldst = &sbuf[bufi][((size_t)rowQuad + (uint32_t)lane) * 4];
            __builtin_amdgcn_global_load_lds(
                (__attribute__((address_space(1))) void*)(void*)const_cast<float*>(gsrc),
                (__attribute__((address_space(3))) void*)(void*)ldst,
                16, 0, 0);
        }
    };

    stage(0, 0);
    __syncthreads();   // vmcnt(0) drained before barrier

    const int g   = lane >> 4;
    const int sub = lane & 15;
    const int slotInTile = wave * 4 + g;           // 0..15

    for (int t = 0; t < NT; ++t) {
        if (t + 1 < NT) stage((t + 1) & 1, t + 1);  // prefetch under compute
        const float* buf = sbuf[t & 1];

        const uint32_t baseQuad = (uint32_t)slotInTile * 96 + (uint32_t)sub * 6;
        float f[24];
#pragma unroll
        for (int j = 0; j < 6; ++j) {
            const uint32_t pq = swz(baseQuad + (uint32_t)j);
            const float4 q = *reinterpret_cast<const float4*>(&buf[pq * 4]);
            f[4 * j + 0] = q.x; f[4 * j + 1] = q.y;
            f[4 * j + 2] = q.z; f[4 * j + 3] = q.w;
        }

        float m[8];
#pragma unroll
        for (int k = 0; k < 8; ++k) m[k] = 0.0f;
        accum8(f, m);
        reduce16(m);

        if (sub == 0) {
            const int slot = t * TILE_B + slotInTile;
#pragma unroll
            for (int k = 0; k < 8; ++k) sA[slot][k] = m[k];
        }
        __syncthreads();  // tile t consumed; tile t+1 loads landed
    }

    // ---- tail: one full wave, 1 thread/batch f32 3x3 Jacobi ----
    if (tid < BPB) {
        const int b = blockIdx.x * BPB + tid;
        if (b < B) {
            float m[8];
#pragma unroll
            for (int k = 0; k < 8; ++k) m[k] = sA[tid][k];

            float A[3][3], V[3][3];
            A[0][0] = m[0] + 1e-05f;
            A[0][1] = m[1]; A[1][0] = m[1];
            A[0][2] = m[2]; A[2][0] = m[2];
            A[1][1] = m[3] + 2e-05f;
            A[1][2] = m[4]; A[2][1] = m[4];
            // trace identity: sum of squared unit norms = 128
            A[2][2] = (128.0f - m[0] - m[3]) + 3e-05f;
#pragma unroll
            for (int i = 0; i < 3; ++i)
#pragma unroll
                for (int j = 0; j < 3; ++j) V[i][j] = (i == j) ? 1.0f : 0.0f;

#pragma unroll
            for (int sweep = 0; sweep < 4; ++sweep) {   // 12 rotations
                jrot<0, 1, 2>(A, V);
                jrot<0, 2, 1>(A, V);
                jrot<1, 2, 0>(A, V);
            }

            float e0 = A[0][0], e1 = A[1][1], e2 = A[2][2];
            float c0x = V[0][0], c0y = V[1][0], c0z = V[2][0];
            float c1x = V[0][1], c1y = V[1][1], c1z = V[2][1];
            float c2x = V[0][2], c2y = V[1][2], c2z = V[2][2];

#define CSWAP(ea, eb, ax, ay, az, bx, by, bz)                         \
            if (ea > eb) {                                            \
                float t_;                                             \
                t_ = ea; ea = eb; eb = t_;                            \
                t_ = ax; ax = bx; bx = t_;                            \
                t_ = ay; ay = by; by = t_;                            \
                t_ = az; az = bz; bz = t_;                            \
            }
            CSWAP(e0, e1, c0x, c0y, c0z, c1x, c1y, c1z)
            CSWAP(e1, e2, c1x, c1y, c1z, c2x, c2y, c2z)
            CSWAP(e0, e1, c0x, c0y, c0z, c1x, c1y, c1z)
#undef CSWAP

            float s0 = m[5], s1 = m[6], s2 = m[7];
            float d1 = s0 * c0x + s1 * c0y + s2 * c0z;
            float f1 = (d1 < 0.0f) ? -1.0f : 1.0f;
            c0x *= f1; c0y *= f1; c0z *= f1;
            float d2 = s0 * c1x + s1 * c1y + s2 * c1z;
            float f2 = (d2 < 0.0f) ? -1.0f : 1.0f;
            c1x *= f2; c1y *= f2; c1z *= f2;

            float v3x = c0y * c1z - c0z * c1y;
            float v3y = c0z * c1x - c0x * c1z;
            float v3z = c0x * c1y - c0y * c1x;

            // stage frame in LDS for coalesced store
            sA[tid][0] = c0x; sA[tid][1] = c1x; sA[tid][2] = v3x;
            sA[tid][3] = c0y; sA[tid][4] = c1y; sA[tid][5] = v3y;
            sA[tid][6] = c0z; sA[tid][7] = c1z; sA[tid][8] = v3z;
        }
    }

    __syncthreads();

    // coalesced epilogue: BPB*9 = 576 floats = 144 dwordx4
    const int blockBase = blockIdx.x * BPB;
    if (blockBase + BPB <= B) {
        if (tid < (BPB * 9) / 4) {
            const float4* s4 = reinterpret_cast<const float4*>(&sA[0][0]);
            float4* o4 = reinterpret_cast<float4*>(out + (size_t)blockBase * 9);
            o4[tid] = s4[tid];
        }
    } else if (tid < BPB) {                 // ragged last block fallback
        const int b = blockBase + tid;
        if (b < B) {
            float* o = out + (size_t)b * 9;
#pragma unroll
            for (int k = 0; k < 9; ++k) o[k] = sA[tid][k];
        }
    }
}

extern "C" void kernel_launch(void* const* d_in, const int* in_sizes, int n_in,
                              void* d_out, int out_size, void* d_ws, size_t ws_size,
                              hipStream_t stream) {
    const float* vf = (const float*)d_in[0];
    float* out = (float*)d_out;
    const int B = in_sizes[0] / 384;   // 128 vectors * 3 components
    const int grid = (B + BPB - 1) / BPB;
    vn_fused<<<dim3(grid), dim3(BLOCK), 0, stream>>>(vf, out, B);
}